// Round 11
// baseline (330.113 us; speedup 1.0000x reference)
//
#include <hip/hip_runtime.h>

typedef __attribute__((ext_vector_type(8))) short bf16x8;
typedef __attribute__((ext_vector_type(4))) float f32x4;
typedef __attribute__((ext_vector_type(4))) float f32x4v;
typedef __attribute__((ext_vector_type(4))) int i32x4;

#define MFMA16(a,b,c) __builtin_amdgcn_mfma_f32_16x16x32_bf16((a),(b),(c),0,0,0)

__device__ __forceinline__ short f2bf(float f){
  unsigned u = __builtin_bit_cast(unsigned, f);
  u += 0x7fffu + ((u >> 16) & 1u);   // round-to-nearest-even
  return (short)(u >> 16);
}

__device__ __forceinline__ void gload16(const void* g, void* l){
  __builtin_amdgcn_global_load_lds((const __attribute__((address_space(1))) unsigned*)g,
                                   (__attribute__((address_space(3))) unsigned*)l,
                                   16, 0, 0);
}

// pack hi16 of two f32 (with rounding) into one dword: [lo16=a, hi16=b]
__device__ __forceinline__ int packbf(float a, float b){
  unsigned ua = __builtin_bit_cast(unsigned, a) + 0x7fffu;
  unsigned ub = __builtin_bit_cast(unsigned, b) + 0x7fffu;
  return __builtin_amdgcn_perm(ub, ua, 0x07060302);  // bytes: ua[3:2], ub[3:2]
}

// ---------------- fp32 -> bf16 elementwise convert (vectorized) ----------------
__global__ __launch_bounds__(256) void k_f2bf(const float* __restrict__ in,
                                              short* __restrict__ out, int n8){
  int i = blockIdx.x * 256 + threadIdx.x;
  if (i >= n8) return;
  f32x4v a = ((const f32x4v*)in)[i*2];
  f32x4v b = ((const f32x4v*)in)[i*2+1];
  bf16x8 o;
  o[0]=f2bf(a[0]); o[1]=f2bf(a[1]); o[2]=f2bf(a[2]); o[3]=f2bf(a[3]);
  o[4]=f2bf(b[0]); o[5]=f2bf(b[1]); o[6]=f2bf(b[2]); o[7]=f2bf(b[3]);
  ((bf16x8*)out)[i] = o;
}

// ---------------- weight transpose + convert: Wt[n][k] = bf16(W[k][n]) ----------------
__global__ __launch_bounds__(256) void k_prep_wT(const float* __restrict__ W,
                                                 short* __restrict__ Wt, int K, int N){
  int i = blockIdx.x * 256 + threadIdx.x;
  int total = (K >> 3) * N;
  if (i >= total) return;
  int n  = i % N;
  int k0 = (i / N) << 3;
  bf16x8 o;
#pragma unroll
  for (int j = 0; j < 8; ++j) o[j] = f2bf(W[(size_t)(k0 + j) * N + n]);
  *(bf16x8*)&Wt[(size_t)n * K + k0] = o;
}

// ---------------- 128x128-tile bf16 GEMM, tri-buffered, counted vmcnt (R5-exact) ----
template<int MODE>
__global__ __launch_bounds__(256, 4) void k_gemm(
    const short* __restrict__ A, const short* __restrict__ Bt,
    const float* __restrict__ bias, float scale,
    void* __restrict__ out0, void* __restrict__ out1,
    int M, int N, int K)
{
  __shared__ __align__(16) short Alds[3][128 * 32];
  __shared__ __align__(16) short Blds[3][128 * 32];
  const int tid = threadIdx.x;
  const int l = tid & 63, w = tid >> 6;
  const int wr = w >> 1, wc = w & 1;
  const int lr = l & 15, lg = l >> 4;

  const int nx = gridDim.x;
  const int nwg = nx * gridDim.y;
  int flat = blockIdx.y * nx + blockIdx.x;
  int u = (flat & 7) * (nwg >> 3) + (flat >> 3);
  const int m0 = (u / nx) * 128, n0 = (u % nx) * 128;

  const int srow = l >> 2;
  const int scol = 8 * ((l & 3) ^ ((l >> 3) & 3));
  const int acol = 8 * (lg ^ ((lr >> 1) & 3));

  f32x4 acc[4][4];
#pragma unroll
  for (int a = 0; a < 4; ++a)
#pragma unroll
    for (int b = 0; b < 4; ++b) acc[a][b] = (f32x4)(0.0f);

  const int nk = K >> 5;
  auto stage = [&](int kt, int slot){
    int k0 = kt << 5;
#pragma unroll
    for (int i = 0; i < 4; ++i){
      int c = w * 4 + i;
      if (c < 8){
        int m = c * 16 + srow;
        gload16(A + (size_t)(m0 + m) * K + k0 + scol, &Alds[slot][c * 512]);
      } else {
        int n = (c - 8) * 16 + srow;
        gload16(Bt + (size_t)(n0 + n) * K + k0 + scol, &Blds[slot][(c - 8) * 512]);
      }
    }
  };

  stage(0, 0);
  stage(1, 1);
  int rd = 0;
  for (int kt = 0; kt < nk; ++kt){
    asm volatile("s_waitcnt vmcnt(4)" ::: "memory");
    __builtin_amdgcn_s_barrier();
    __builtin_amdgcn_sched_barrier(0);
    int tt = (kt + 2 < nk) ? kt + 2 : nk - 1;
    int tgt = rd + 2; if (tgt >= 3) tgt -= 3;
    stage(tt, tgt);

    bf16x8 af[4], bfv[4];
#pragma unroll
    for (int mi = 0; mi < 4; ++mi){
      int row = wr * 64 + mi * 16 + lr;
      af[mi] = *(const bf16x8*)&Alds[rd][row * 32 + acol];
    }
#pragma unroll
    for (int ni = 0; ni < 4; ++ni){
      int row = wc * 64 + ni * 16 + lr;
      bfv[ni] = *(const bf16x8*)&Blds[rd][row * 32 + acol];
    }
#pragma unroll
    for (int mi = 0; mi < 4; ++mi)
#pragma unroll
      for (int ni = 0; ni < 4; ++ni)
        acc[mi][ni] = MFMA16(af[mi], bfv[ni], acc[mi][ni]);

    if (++rd == 3) rd = 0;
  }
  asm volatile("s_waitcnt vmcnt(0)" ::: "memory");

#pragma unroll
  for (int mi = 0; mi < 4; ++mi)
#pragma unroll
    for (int ni = 0; ni < 4; ++ni){
      int col = n0 + wc * 64 + ni * 16 + lr;
      float bv = bias[col];
#pragma unroll
      for (int r = 0; r < 4; ++r){
        int row = m0 + wr * 64 + mi * 16 + lg * 4 + r;
        float v = acc[mi][ni][r] + bv;
        if (MODE == 0){
          v *= scale;
          int b = row >> 10, lp = row & 1023;
          int h = lp >> 7;
          int lq = ((lp & 127) << 3) | (col >> 7);
          int dh = col & 127;
          ((short*)out0)[(((size_t)(b * 8 + h)) * 1024 + lq) * 128 + dh] = f2bf(v);
        } else {
          ((float*)out0)[(size_t)row * N + col] = v;
        }
      }
    }
}

// ---------------- KV GEMM: 256x256, 8 waves, tri-buffered (R8-exact) ----------------
__global__ __launch_bounds__(512, 2) void k_gemmKV(
    const short* __restrict__ A, const short* __restrict__ Bt,
    const float* __restrict__ bias,
    short* __restrict__ out0, short* __restrict__ out1)
{
  __shared__ __align__(16) short As[3][256 * 32];
  __shared__ __align__(16) short Bs[3][256 * 32];
  const int tid = threadIdx.x;
  const int l = tid & 63, w = tid >> 6;
  const int lr = l & 15, lg = l >> 4;
  const int wm = w >> 2, wn = w & 3;

  // R8 bijective XCD-chunked remap (each XCD: 8 m-panels x 8 n-panels)
  int flat = blockIdx.y * 8 + blockIdx.x;
  int u = (flat & 7) * 64 + (flat >> 3);
  const int m0 = (u >> 3) * 256, n0 = (u & 7) * 256;

  const int srow = l >> 2;
  const int scol = 8 * ((l & 3) ^ ((l >> 3) & 3));
  const int acol = 8 * (lg ^ ((lr >> 1) & 3));

  f32x4 acc[8][4];
#pragma unroll
  for (int a = 0; a < 8; ++a)
#pragma unroll
    for (int b = 0; b < 4; ++b) acc[a][b] = (f32x4)(0.0f);

  auto stage = [&](int kt, int slot){
    int k0 = kt << 5;
#pragma unroll
    for (int i = 0; i < 4; ++i){
      int c = w * 4 + i;
      if (c < 16){
        int m = c * 16 + srow;
        gload16(A + (size_t)(m0 + m) * 1024 + k0 + scol, &As[slot][c * 512]);
      } else {
        int n = (c - 16) * 16 + srow;
        gload16(Bt + (size_t)(n0 + n) * 1024 + k0 + scol, &Bs[slot][(c - 16) * 512]);
      }
    }
  };

  stage(0, 0);
  stage(1, 1);
  int rd = 0;
  for (int kt = 0; kt < 32; ++kt){
    asm volatile("s_waitcnt vmcnt(4)" ::: "memory");
    __builtin_amdgcn_s_barrier();
    __builtin_amdgcn_sched_barrier(0);
    int tt = (kt + 2 < 32) ? kt + 2 : 31;
    int tgt = rd + 2; if (tgt >= 3) tgt -= 3;
    stage(tt, tgt);

    bf16x8 af[8], bfv[4];
#pragma unroll
    for (int mi = 0; mi < 8; ++mi){
      int row = wm * 128 + mi * 16 + lr;
      af[mi] = *(const bf16x8*)&As[rd][row * 32 + acol];
    }
#pragma unroll
    for (int ni = 0; ni < 4; ++ni){
      int row = wn * 64 + ni * 16 + lr;
      bfv[ni] = *(const bf16x8*)&Bs[rd][row * 32 + acol];
    }
    __builtin_amdgcn_s_setprio(1);
#pragma unroll
    for (int mi = 0; mi < 8; ++mi)
#pragma unroll
      for (int ni = 0; ni < 4; ++ni)
        acc[mi][ni] = MFMA16(af[mi], bfv[ni], acc[mi][ni]);
    __builtin_amdgcn_s_setprio(0);

    if (++rd == 3) rd = 0;
  }
  asm volatile("s_waitcnt vmcnt(0)" ::: "memory");

#pragma unroll
  for (int mi = 0; mi < 8; ++mi)
#pragma unroll
    for (int ni = 0; ni < 4; ++ni){
      int col = n0 + wn * 64 + ni * 16 + lr;
      float bv = bias[col];
#pragma unroll
      for (int r = 0; r < 4; ++r){
        int row = m0 + wm * 128 + mi * 16 + lg * 4 + r;
        float v = acc[mi][ni][r] + bv;
        int b = row >> 11, nn = row & 2047;
        if (col < 1024){
          int h = col >> 7, dh = col & 127;
          out0[(((size_t)(b * 8 + h)) * 2048 + nn) * 128 + dh] = f2bf(v);
        } else {
          int c2 = col - 1024, h = c2 >> 7, dh = c2 & 127;
          out1[(((size_t)(b * 8 + h)) * 128 + dh) * 2048 + nn] = f2bf(v);
        }
      }
    }
}

// ---------------- flash attention: swapped QK^T, in-register P, V DIRECT-FROM-GLOBAL
// Q[bh][1024][128], K[bh][2048][128], Vt[bh][128][2048]; logits in log2 units.
// 4 waves x 32 q = 128 q/block; K double-buffered in LDS (32KB); V fragments are
// plain global loads (L2-resident, XCD-local via bh swizzle) preloaded at iter top
// so QK^T+softmax (~600cy) hides their latency. LDS-pipe ops/tile: 48 -> 32.
__global__ __launch_bounds__(256, 2) void k_attn(
    const short* __restrict__ Q, const short* __restrict__ K,
    const short* __restrict__ Vt, short* __restrict__ O)
{
  __shared__ __align__(16) short Klds[2][64 * 128];   // [key][dh^swz], 16KB each
  const int tid = threadIdx.x;
  const int l = tid & 63, w = tid >> 6;
  const int lr = l & 15, lg = l >> 4;

  // XCD-chunked remap: grid (8,64) = 512 blocks; each XCD owns 8 consecutive bh
  int flat = blockIdx.y * 8 + blockIdx.x;
  int xcd = flat & 7, idx = flat >> 3;          // idx in [0,64)
  int bh = xcd * 8 + (idx >> 3);
  int q0 = (idx & 7) * 128;
  const int qbase = q0 + w * 32;

  const short* Qb = Q  + (size_t)bh * 1024 * 128;
  const short* Kb = K  + (size_t)bh * 2048 * 128;
  const short* Vb = Vt + (size_t)bh * 128 * 2048;

  // Q fragments (B operand): col=q=lr, k = kc*32 + lg*8 + e
  bf16x8 qf[2][4];
#pragma unroll
  for (int mi = 0; mi < 2; ++mi)
#pragma unroll
    for (int kc = 0; kc < 4; ++kc)
      qf[mi][kc] = *(const bf16x8*)&Qb[(size_t)(qbase + mi * 16 + lr) * 128 + kc * 32 + lg * 8];

  f32x4 acc[2][8];
#pragma unroll
  for (int mi = 0; mi < 2; ++mi)
#pragma unroll
    for (int d = 0; d < 8; ++d) acc[mi][d] = (f32x4)(0.0f);
  float mrun[2] = {-3e38f, -3e38f}, lsum[2] = {0.f, 0.f};

  const int addrA = 4 * ((l & 15) + 32 * ((l >> 4) & 1));
  const int addrB = addrA + 64;
  const bool hi = (l >= 32);

  auto stageK = [&](int t, int buf){
    int kv0 = t * 64;
#pragma unroll
    for (int i = 0; i < 4; ++i){
      int c = w * 4 + i;
      int row = 4 * c + (l >> 4);
      int col = ((l & 15) * 8) ^ ((row & 7) * 8);
      gload16(Kb + (size_t)(kv0 + row) * 128 + col, &Klds[buf][c * 512]);
    }
  };

  stageK(0, 0);
  __syncthreads();
  int cur = 0;
  const int swz = (lr & 7) * 8;
  // per-lane V base: row = d*16+lr, key offset = kc*32 + lg*8
  const short* Vlane = Vb + (size_t)lr * 2048 + lg * 8;

  for (int t = 0; t < 32; ++t){
    const int kv0 = t * 64;
    if (t + 1 < 32) stageK(t + 1, cur ^ 1);

    // ---- preload all 16 V fragments for this tile (global, L2-served)
    bf16x8 vf[8][2];
#pragma unroll
    for (int d = 0; d < 8; ++d)
#pragma unroll
      for (int kc = 0; kc < 2; ++kc)
        vf[d][kc] = *(const bf16x8*)&Vlane[(size_t)d * 16 * 2048 + kv0 + kc * 32];

    const short* Kl = &Klds[cur][0];

    // ---- QK^T swapped: s[mi][nt][r] = S[key=nt*16+lg*4+r][q=qbase+mi*16+lr]
    f32x4 s[2][4];
    __builtin_amdgcn_s_setprio(1);
#pragma unroll
    for (int nt = 0; nt < 4; ++nt){
      f32x4 s0 = (f32x4)(0.0f), s1 = (f32x4)(0.0f);
#pragma unroll
      for (int kc = 0; kc < 4; ++kc){
        bf16x8 kf = *(const bf16x8*)&Kl[(nt * 16 + lr) * 128 + ((kc * 32 + lg * 8) ^ swz)];
        s0 = MFMA16(kf, qf[0][kc], s0);
        s1 = MFMA16(kf, qf[1][kc], s1);
      }
      s[0][nt] = s0; s[1][nt] = s1;
    }
    __builtin_amdgcn_s_setprio(0);

    // ---- defer-max online softmax (per-lane row-local, THR=8 in log2 units)
    float mloc[2];
    int ok = 1;
#pragma unroll
    for (int mi = 0; mi < 2; ++mi){
      float v = fmaxf(fmaxf(fmaxf(s[mi][0][0], s[mi][0][1]), fmaxf(s[mi][0][2], s[mi][0][3])),
                      fmaxf(fmaxf(s[mi][1][0], s[mi][1][1]), fmaxf(s[mi][1][2], s[mi][1][3])));
      v = fmaxf(v, fmaxf(fmaxf(fmaxf(s[mi][2][0], s[mi][2][1]), fmaxf(s[mi][2][2], s[mi][2][3])),
                         fmaxf(fmaxf(s[mi][3][0], s[mi][3][1]), fmaxf(s[mi][3][2], s[mi][3][3]))));
      mloc[mi] = v;
      ok &= (v <= mrun[mi] + 8.0f) ? 1 : 0;
    }
    if (!__all(ok)){
#pragma unroll
      for (int mi = 0; mi < 2; ++mi){
        float v = mloc[mi];
        v = fmaxf(v, __shfl_xor(v, 16));
        v = fmaxf(v, __shfl_xor(v, 32));
        float mnew = fmaxf(mrun[mi], v);
        float sc = exp2f(mrun[mi] - mnew);
        mrun[mi] = mnew;
        lsum[mi] *= sc;
#pragma unroll
        for (int r = 0; r < 4; ++r){
          float scr = __shfl(sc, 20 * lg + r);
#pragma unroll
          for (int d = 0; d < 8; ++d) acc[mi][d][r] *= scr;
        }
      }
    }

    // ---- P = exp2(S - mrun), pack pairs
    int pk[2][4][2];
#pragma unroll
    for (int mi = 0; mi < 2; ++mi){
      float ls = 0.f;
#pragma unroll
      for (int nt = 0; nt < 4; ++nt){
        float p0 = exp2f(s[mi][nt][0] - mrun[mi]);
        float p1 = exp2f(s[mi][nt][1] - mrun[mi]);
        float p2 = exp2f(s[mi][nt][2] - mrun[mi]);
        float p3 = exp2f(s[mi][nt][3] - mrun[mi]);
        ls += (p0 + p1) + (p2 + p3);
        pk[mi][nt][0] = packbf(p0, p1);
        pk[mi][nt][1] = packbf(p2, p3);
      }
      lsum[mi] += ls;
    }

    // ---- exchange to PV A-operand layout via ds_bpermute
    bf16x8 pa[2][2];
#pragma unroll
    for (int mi = 0; mi < 2; ++mi)
#pragma unroll
      for (int kc = 0; kc < 2; ++kc){
        i32x4 dw;
#pragma unroll
        for (int av = 0; av < 2; ++av){
          int addr = av ? addrB : addrA;
#pragma unroll
          for (int jj = 0; jj < 2; ++jj){
            int t0 = __builtin_amdgcn_ds_bpermute(addr, pk[mi][2 * kc][jj]);
            int t1 = __builtin_amdgcn_ds_bpermute(addr, pk[mi][2 * kc + 1][jj]);
            dw[av * 2 + jj] = hi ? t1 : t0;
          }
        }
        pa[mi][kc] = __builtin_bit_cast(bf16x8, dw);
      }

    // ---- PV: O += P @ V  (V fragments from registers)
    __builtin_amdgcn_s_setprio(1);
#pragma unroll
    for (int d = 0; d < 8; ++d)
#pragma unroll
      for (int kc = 0; kc < 2; ++kc){
        acc[0][d] = MFMA16(pa[0][kc], vf[d][kc], acc[0][d]);
        acc[1][d] = MFMA16(pa[1][kc], vf[d][kc], acc[1][d]);
      }
    __builtin_amdgcn_s_setprio(0);

    __syncthreads();
    cur ^= 1;
  }

  // ---- epilogue: full row-sum for q=lr, redistribute to acc rows, store
  const int b = bh >> 3, h = bh & 7;
#pragma unroll
  for (int mi = 0; mi < 2; ++mi){
    float ls = lsum[mi];
    ls += __shfl_xor(ls, 16);
    ls += __shfl_xor(ls, 32);
    float inv = 1.0f / ls;
#pragma unroll
    for (int r = 0; r < 4; ++r){
      float invr = __shfl(inv, 20 * lg + r);
      int grow = qbase + mi * 16 + lg * 4 + r;
      size_t base = ((size_t)b * 1024 + (size_t)h * 128 + (grow >> 3)) * 1024
                  + (size_t)(grow & 7) * 128;
#pragma unroll
      for (int d = 0; d < 8; ++d)
        O[base + d * 16 + lr] = f2bf(acc[mi][d][r] * invr);
    }
  }
}

extern "C" void kernel_launch(void* const* d_in, const int* in_sizes, int n_in,
                              void* d_out, int out_size, void* d_ws, size_t ws_size,
                              hipStream_t stream){
  const float* motion = (const float*)d_in[0];
  const float* scene  = (const float*)d_in[1];
  const float* Wq     = (const float*)d_in[2];
  const float* bq     = (const float*)d_in[3];
  const float* Wkv    = (const float*)d_in[4];
  const float* bkv    = (const float*)d_in[5];
  const float* Wout   = (const float*)d_in[6];
  const float* bout   = (const float*)d_in[7];
  float* out = (float*)d_out;

  char* ws = (char*)d_ws;
  const size_t MB = 1024 * 1024;
  short* WqT   = (short*)(ws + 0);        // 2 MB
  short* WkvT  = (short*)(ws + 2  * MB);  // 4 MB
  short* WoutT = (short*)(ws + 6  * MB);  // 2 MB
  short* mA    = (short*)(ws + 8  * MB);  // 16 MB motion bf16 (reused as attnO)
  short* sA    = (short*)(ws + 24 * MB);  // 32 MB scene bf16
  short* Qb    = (short*)(ws + 56 * MB);  // 16 MB
  short* Kb    = (short*)(ws + 72 * MB);  // 32 MB
  short* Vtb   = (short*)(ws + 104* MB);  // 32 MB  V transposed [bh][dh][n]
  short* attnO = mA;

  const float qscale = 0.03125f * 1.44269504088896341f;  // D^-0.5 * log2(e)

  k_prep_wT<<<dim3(512),  256, 0, stream>>>(Wq,   WqT,   1024, 1024);
  k_prep_wT<<<dim3(1024), 256, 0, stream>>>(Wkv,  WkvT,  1024, 2048);
  k_prep_wT<<<dim3(512),  256, 0, stream>>>(Wout, WoutT, 1024, 1024);
  k_f2bf<<<dim3(4096), 256, 0, stream>>>(motion, mA, 1024 * 1024);
  k_f2bf<<<dim3(8192), 256, 0, stream>>>(scene,  sA, 2 * 1024 * 1024);

  k_gemm<0><<<dim3(8, 64), 256, 0, stream>>>(mA, WqT, bq, qscale, Qb, nullptr, 8192, 1024, 1024);
  k_gemmKV<<<dim3(8, 64), 512, 0, stream>>>(sA, WkvT, bkv, Kb, Vtb);
  k_attn<<<dim3(8, 64), 256, 0, stream>>>(Qb, Kb, Vtb, attnO);
  k_gemm<2><<<dim3(8, 64), 256, 0, stream>>>(attnO, WoutT, bout, 1.0f, out, nullptr, 8192, 1024, 1024);
}

// Round 12
// 294.849 us; speedup vs baseline: 1.1196x; 1.1196x over previous
//
#include <hip/hip_runtime.h>

typedef __attribute__((ext_vector_type(8))) short bf16x8;
typedef __attribute__((ext_vector_type(4))) float f32x4;
typedef __attribute__((ext_vector_type(4))) float f32x4v;
typedef __attribute__((ext_vector_type(4))) int i32x4;

#define MFMA16(a,b,c) __builtin_amdgcn_mfma_f32_16x16x32_bf16((a),(b),(c),0,0,0)

__device__ __forceinline__ short f2bf(float f){
  unsigned u = __builtin_bit_cast(unsigned, f);
  u += 0x7fffu + ((u >> 16) & 1u);   // round-to-nearest-even
  return (short)(u >> 16);
}

__device__ __forceinline__ void gload16(const void* g, void* l){
  __builtin_amdgcn_global_load_lds((const __attribute__((address_space(1))) unsigned*)g,
                                   (__attribute__((address_space(3))) unsigned*)l,
                                   16, 0, 0);
}

// pack hi16 of two f32 (with rounding) into one dword: [lo16=a, hi16=b]
__device__ __forceinline__ int packbf(float a, float b){
  unsigned ua = __builtin_bit_cast(unsigned, a) + 0x7fffu;
  unsigned ub = __builtin_bit_cast(unsigned, b) + 0x7fffu;
  return __builtin_amdgcn_perm(ub, ua, 0x07060302);  // bytes: ua[3:2], ub[3:2]
}

// -------- fused fp32 -> bf16 convert: blocks 0..4095 motion, 4096..12287 scene --------
__global__ __launch_bounds__(256) void k_f2bf_all(const float* __restrict__ motion,
                                                  const float* __restrict__ scene,
                                                  short* __restrict__ mOut,
                                                  short* __restrict__ sOut){
  int blk = blockIdx.x;
  const float* in; short* out; int i;
  if (blk < 4096){ in = motion; out = mOut; i = blk * 256 + threadIdx.x; }
  else           { in = scene;  out = sOut; i = (blk - 4096) * 256 + threadIdx.x; }
  f32x4v a = ((const f32x4v*)in)[i*2];
  f32x4v b = ((const f32x4v*)in)[i*2+1];
  bf16x8 o;
  o[0]=f2bf(a[0]); o[1]=f2bf(a[1]); o[2]=f2bf(a[2]); o[3]=f2bf(a[3]);
  o[4]=f2bf(b[0]); o[5]=f2bf(b[1]); o[6]=f2bf(b[2]); o[7]=f2bf(b[3]);
  ((bf16x8*)out)[i] = o;
}

// -------- fused weight transpose+convert: Wt[n][k] = bf16(W[k][n]) for 3 weights ------
// blocks 0..511 Wq (1024x1024), 512..1535 Wkv (1024x2048), 1536..2047 Wout (1024x1024)
__global__ __launch_bounds__(256) void k_prep_all(const float* __restrict__ Wq,
                                                  const float* __restrict__ Wkv,
                                                  const float* __restrict__ Wout,
                                                  short* __restrict__ WqT,
                                                  short* __restrict__ WkvT,
                                                  short* __restrict__ WoutT){
  int blk = blockIdx.x;
  const float* W; short* Wt; int N, i;
  if (blk < 512)       { W = Wq;   Wt = WqT;   N = 1024; i = blk * 256 + threadIdx.x; }
  else if (blk < 1536) { W = Wkv;  Wt = WkvT;  N = 2048; i = (blk - 512) * 256 + threadIdx.x; }
  else                 { W = Wout; Wt = WoutT; N = 1024; i = (blk - 1536) * 256 + threadIdx.x; }
  int n  = i % N;
  int k0 = (i / N) << 3;
  bf16x8 o;
#pragma unroll
  for (int j = 0; j < 8; ++j) o[j] = f2bf(W[(size_t)(k0 + j) * N + n]);
  *(bf16x8*)&Wt[(size_t)n * 1024 + k0] = o;
}

// ---------------- 128x128-tile bf16 GEMM, tri-buffered, counted vmcnt (R5-exact) ----
// MODE 0: Q proj  -> Qb bf16 [b][h][l][dh] via the reference's DIRECT reshape
// MODE 2: out proj-> fp32 d_out
template<int MODE>
__global__ __launch_bounds__(256, 4) void k_gemm(
    const short* __restrict__ A, const short* __restrict__ Bt,
    const float* __restrict__ bias, float scale,
    void* __restrict__ out0, void* __restrict__ out1,
    int M, int N, int K)
{
  __shared__ __align__(16) short Alds[3][128 * 32];
  __shared__ __align__(16) short Blds[3][128 * 32];
  const int tid = threadIdx.x;
  const int l = tid & 63, w = tid >> 6;
  const int wr = w >> 1, wc = w & 1;
  const int lr = l & 15, lg = l >> 4;

  const int nx = gridDim.x;
  const int nwg = nx * gridDim.y;
  int flat = blockIdx.y * nx + blockIdx.x;
  int u = (flat & 7) * (nwg >> 3) + (flat >> 3);
  const int m0 = (u / nx) * 128, n0 = (u % nx) * 128;

  const int srow = l >> 2;
  const int scol = 8 * ((l & 3) ^ ((l >> 3) & 3));
  const int acol = 8 * (lg ^ ((lr >> 1) & 3));

  f32x4 acc[4][4];
#pragma unroll
  for (int a = 0; a < 4; ++a)
#pragma unroll
    for (int b = 0; b < 4; ++b) acc[a][b] = (f32x4)(0.0f);

  const int nk = K >> 5;
  auto stage = [&](int kt, int slot){
    int k0 = kt << 5;
#pragma unroll
    for (int i = 0; i < 4; ++i){
      int c = w * 4 + i;
      if (c < 8){
        int m = c * 16 + srow;
        gload16(A + (size_t)(m0 + m) * K + k0 + scol, &Alds[slot][c * 512]);
      } else {
        int n = (c - 8) * 16 + srow;
        gload16(Bt + (size_t)(n0 + n) * K + k0 + scol, &Blds[slot][(c - 8) * 512]);
      }
    }
  };

  stage(0, 0);
  stage(1, 1);
  int rd = 0;
  for (int kt = 0; kt < nk; ++kt){
    asm volatile("s_waitcnt vmcnt(4)" ::: "memory");
    __builtin_amdgcn_s_barrier();
    __builtin_amdgcn_sched_barrier(0);
    int tt = (kt + 2 < nk) ? kt + 2 : nk - 1;
    int tgt = rd + 2; if (tgt >= 3) tgt -= 3;
    stage(tt, tgt);

    bf16x8 af[4], bfv[4];
#pragma unroll
    for (int mi = 0; mi < 4; ++mi){
      int row = wr * 64 + mi * 16 + lr;
      af[mi] = *(const bf16x8*)&Alds[rd][row * 32 + acol];
    }
#pragma unroll
    for (int ni = 0; ni < 4; ++ni){
      int row = wc * 64 + ni * 16 + lr;
      bfv[ni] = *(const bf16x8*)&Blds[rd][row * 32 + acol];
    }
#pragma unroll
    for (int mi = 0; mi < 4; ++mi)
#pragma unroll
      for (int ni = 0; ni < 4; ++ni)
        acc[mi][ni] = MFMA16(af[mi], bfv[ni], acc[mi][ni]);

    if (++rd == 3) rd = 0;
  }
  asm volatile("s_waitcnt vmcnt(0)" ::: "memory");

#pragma unroll
  for (int mi = 0; mi < 4; ++mi)
#pragma unroll
    for (int ni = 0; ni < 4; ++ni){
      int col = n0 + wc * 64 + ni * 16 + lr;
      float bv = bias[col];
#pragma unroll
      for (int r = 0; r < 4; ++r){
        int row = m0 + wr * 64 + mi * 16 + lg * 4 + r;
        float v = acc[mi][ni][r] + bv;
        if (MODE == 0){
          v *= scale;
          int b = row >> 10, lp = row & 1023;
          int h = lp >> 7;
          int lq = ((lp & 127) << 3) | (col >> 7);
          int dh = col & 127;
          ((short*)out0)[(((size_t)(b * 8 + h)) * 1024 + lq) * 128 + dh] = f2bf(v);
        } else {
          ((float*)out0)[(size_t)row * N + col] = v;
        }
      }
    }
}

// ---------------- KV GEMM: 256x256, 8 waves, tri-buffered (R8-exact) ----------------
__global__ __launch_bounds__(512, 2) void k_gemmKV(
    const short* __restrict__ A, const short* __restrict__ Bt,
    const float* __restrict__ bias,
    short* __restrict__ out0, short* __restrict__ out1)
{
  __shared__ __align__(16) short As[3][256 * 32];
  __shared__ __align__(16) short Bs[3][256 * 32];
  const int tid = threadIdx.x;
  const int l = tid & 63, w = tid >> 6;
  const int lr = l & 15, lg = l >> 4;
  const int wm = w >> 2, wn = w & 3;

  // R8 bijective XCD-chunked remap (each XCD: 8 m-panels x 8 n-panels)
  int flat = blockIdx.y * 8 + blockIdx.x;
  int u = (flat & 7) * 64 + (flat >> 3);
  const int m0 = (u >> 3) * 256, n0 = (u & 7) * 256;

  const int srow = l >> 2;
  const int scol = 8 * ((l & 3) ^ ((l >> 3) & 3));
  const int acol = 8 * (lg ^ ((lr >> 1) & 3));

  f32x4 acc[8][4];
#pragma unroll
  for (int a = 0; a < 8; ++a)
#pragma unroll
    for (int b = 0; b < 4; ++b) acc[a][b] = (f32x4)(0.0f);

  auto stage = [&](int kt, int slot){
    int k0 = kt << 5;
#pragma unroll
    for (int i = 0; i < 4; ++i){
      int c = w * 4 + i;
      if (c < 16){
        int m = c * 16 + srow;
        gload16(A + (size_t)(m0 + m) * 1024 + k0 + scol, &As[slot][c * 512]);
      } else {
        int n = (c - 16) * 16 + srow;
        gload16(Bt + (size_t)(n0 + n) * 1024 + k0 + scol, &Bs[slot][(c - 16) * 512]);
      }
    }
  };

  stage(0, 0);
  stage(1, 1);
  int rd = 0;
  for (int kt = 0; kt < 32; ++kt){
    asm volatile("s_waitcnt vmcnt(4)" ::: "memory");
    __builtin_amdgcn_s_barrier();
    __builtin_amdgcn_sched_barrier(0);
    int tt = (kt + 2 < 32) ? kt + 2 : 31;
    int tgt = rd + 2; if (tgt >= 3) tgt -= 3;
    stage(tt, tgt);

    bf16x8 af[8], bfv[4];
#pragma unroll
    for (int mi = 0; mi < 8; ++mi){
      int row = wm * 128 + mi * 16 + lr;
      af[mi] = *(const bf16x8*)&As[rd][row * 32 + acol];
    }
#pragma unroll
    for (int ni = 0; ni < 4; ++ni){
      int row = wn * 64 + ni * 16 + lr;
      bfv[ni] = *(const bf16x8*)&Bs[rd][row * 32 + acol];
    }
    __builtin_amdgcn_s_setprio(1);
#pragma unroll
    for (int mi = 0; mi < 8; ++mi)
#pragma unroll
      for (int ni = 0; ni < 4; ++ni)
        acc[mi][ni] = MFMA16(af[mi], bfv[ni], acc[mi][ni]);
    __builtin_amdgcn_s_setprio(0);

    if (++rd == 3) rd = 0;
  }
  asm volatile("s_waitcnt vmcnt(0)" ::: "memory");

#pragma unroll
  for (int mi = 0; mi < 8; ++mi)
#pragma unroll
    for (int ni = 0; ni < 4; ++ni){
      int col = n0 + wn * 64 + ni * 16 + lr;
      float bv = bias[col];
#pragma unroll
      for (int r = 0; r < 4; ++r){
        int row = m0 + wm * 128 + mi * 16 + lg * 4 + r;
        float v = acc[mi][ni][r] + bv;
        int b = row >> 11, nn = row & 2047;
        if (col < 1024){
          int h = col >> 7, dh = col & 127;
          out0[(((size_t)(b * 8 + h)) * 2048 + nn) * 128 + dh] = f2bf(v);
        } else {
          int c2 = col - 1024, h = c2 >> 7, dh = c2 & 127;
          out1[(((size_t)(b * 8 + h)) * 128 + dh) * 2048 + nn] = f2bf(v);
        }
      }
    }
}

// ---------------- flash attention (R8-exact: swapped QK^T, in-register P) ----------
// Q[bh][1024][128], K[bh][2048][128], Vt[bh][128][2048]; logits in log2 units.
// 4 waves x 32 q-rows = 128 q/block; grid 512 = 2 blocks/CU (LDS 64KB, no P-LDS).
__global__ __launch_bounds__(256, 2) void k_attn(
    const short* __restrict__ Q, const short* __restrict__ K,
    const short* __restrict__ Vt, short* __restrict__ O)
{
  __shared__ __align__(16) short Klds[2][64 * 128];   // [key][dh^swz], 16KB each
  __shared__ __align__(16) short Vlds[2][128 * 64];   // [dh][key^swz], 16KB each
  const int tid = threadIdx.x;
  const int l = tid & 63, w = tid >> 6;
  const int lr = l & 15, lg = l >> 4;

  // XCD-chunked remap: grid (8,64) = 512 blocks; each XCD owns 8 consecutive bh
  int flat = blockIdx.y * 8 + blockIdx.x;
  int xcd = flat & 7, idx = flat >> 3;          // idx in [0,64)
  int bh = xcd * 8 + (idx >> 3);
  int q0 = (idx & 7) * 128;
  const int qbase = q0 + w * 32;

  const short* Qb = Q  + (size_t)bh * 1024 * 128;
  const short* Kb = K  + (size_t)bh * 2048 * 128;
  const short* Vb = Vt + (size_t)bh * 128 * 2048;

  // Q fragments (B operand): col=q=lr, k = kc*32 + lg*8 + e
  bf16x8 qf[2][4];
#pragma unroll
  for (int mi = 0; mi < 2; ++mi)
#pragma unroll
    for (int kc = 0; kc < 4; ++kc)
      qf[mi][kc] = *(const bf16x8*)&Qb[(size_t)(qbase + mi * 16 + lr) * 128 + kc * 32 + lg * 8];

  f32x4 acc[2][8];
#pragma unroll
  for (int mi = 0; mi < 2; ++mi)
#pragma unroll
    for (int d = 0; d < 8; ++d) acc[mi][d] = (f32x4)(0.0f);
  float mrun[2] = {-3e38f, -3e38f}, lsum[2] = {0.f, 0.f};

  const int addrA = 4 * ((l & 15) + 32 * ((l >> 4) & 1));
  const int addrB = addrA + 64;
  const bool hi = (l >= 32);

  auto stageK = [&](int t, int buf){
    int kv0 = t * 64;
#pragma unroll
    for (int i = 0; i < 4; ++i){
      int c = w * 4 + i;
      int row = 4 * c + (l >> 4);
      int col = ((l & 15) * 8) ^ ((row & 7) * 8);
      gload16(Kb + (size_t)(kv0 + row) * 128 + col, &Klds[buf][c * 512]);
    }
  };
  auto stageV = [&](int t, int buf){
    int kv0 = t * 64;
#pragma unroll
    for (int i = 0; i < 4; ++i){
      int c = w * 4 + i;
      int dh = 8 * c + (l >> 3);
      int col = ((l & 7) * 8) ^ (((l >> 3) & 7) * 8);
      gload16(Vb + (size_t)dh * 2048 + kv0 + col, &Vlds[buf][c * 512]);
    }
  };

  stageK(0, 0); stageV(0, 0);
  __syncthreads();
  int cur = 0;
  const int swz = (lr & 7) * 8;

  for (int t = 0; t < 32; ++t){
    if (t + 1 < 32){ stageK(t + 1, cur ^ 1); stageV(t + 1, cur ^ 1); }
    const short* Kl = &Klds[cur][0];
    const short* Vl = &Vlds[cur][0];

    // ---- QK^T swapped: s[mi][nt][r] = S[key=nt*16+lg*4+r][q=qbase+mi*16+lr]
    f32x4 s[2][4];
    __builtin_amdgcn_s_setprio(1);
#pragma unroll
    for (int nt = 0; nt < 4; ++nt){
      f32x4 s0 = (f32x4)(0.0f), s1 = (f32x4)(0.0f);
#pragma unroll
      for (int kc = 0; kc < 4; ++kc){
        bf16x8 kf = *(const bf16x8*)&Kl[(nt * 16 + lr) * 128 + ((kc * 32 + lg * 8) ^ swz)];
        s0 = MFMA16(kf, qf[0][kc], s0);
        s1 = MFMA16(kf, qf[1][kc], s1);
      }
      s[0][nt] = s0; s[1][nt] = s1;
    }
    __builtin_amdgcn_s_setprio(0);

    // ---- defer-max online softmax (per-lane row-local, THR=8 in log2 units)
    float mloc[2];
    int ok = 1;
#pragma unroll
    for (int mi = 0; mi < 2; ++mi){
      float v = fmaxf(fmaxf(fmaxf(s[mi][0][0], s[mi][0][1]), fmaxf(s[mi][0][2], s[mi][0][3])),
                      fmaxf(fmaxf(s[mi][1][0], s[mi][1][1]), fmaxf(s[mi][1][2], s[mi][1][3])));
      v = fmaxf(v, fmaxf(fmaxf(fmaxf(s[mi][2][0], s[mi][2][1]), fmaxf(s[mi][2][2], s[mi][2][3])),
                         fmaxf(fmaxf(s[mi][3][0], s[mi][3][1]), fmaxf(s[mi][3][2], s[mi][3][3]))));
      mloc[mi] = v;
      ok &= (v <= mrun[mi] + 8.0f) ? 1 : 0;
    }
    if (!__all(ok)){
#pragma unroll
      for (int mi = 0; mi < 2; ++mi){
        float v = mloc[mi];
        v = fmaxf(v, __shfl_xor(v, 16));
        v = fmaxf(v, __shfl_xor(v, 32));
        float mnew = fmaxf(mrun[mi], v);
        float sc = exp2f(mrun[mi] - mnew);
        mrun[mi] = mnew;
        lsum[mi] *= sc;
#pragma unroll
        for (int r = 0; r < 4; ++r){
          float scr = __shfl(sc, 20 * lg + r);
#pragma unroll
          for (int d = 0; d < 8; ++d) acc[mi][d][r] *= scr;
        }
      }
    }

    // ---- P = exp2(S - mrun), pack pairs
    int pk[2][4][2];
#pragma unroll
    for (int mi = 0; mi < 2; ++mi){
      float ls = 0.f;
#pragma unroll
      for (int nt = 0; nt < 4; ++nt){
        float p0 = exp2f(s[mi][nt][0] - mrun[mi]);
        float p1 = exp2f(s[mi][nt][1] - mrun[mi]);
        float p2 = exp2f(s[mi][nt][2] - mrun[mi]);
        float p3 = exp2f(s[mi][nt][3] - mrun[mi]);
        ls += (p0 + p1) + (p2 + p3);
        pk[mi][nt][0] = packbf(p0, p1);
        pk[mi][nt][1] = packbf(p2, p3);
      }
      lsum[mi] += ls;
    }

    // ---- exchange to PV A-operand layout via ds_bpermute
    bf16x8 pa[2][2];
#pragma unroll
    for (int mi = 0; mi < 2; ++mi)
#pragma unroll
      for (int kc = 0; kc < 2; ++kc){
        i32x4 dw;
#pragma unroll
        for (int av = 0; av < 2; ++av){
          int addr = av ? addrB : addrA;
#pragma unroll
          for (int jj = 0; jj < 2; ++jj){
            int t0 = __builtin_amdgcn_ds_bpermute(addr, pk[mi][2 * kc][jj]);
            int t1 = __builtin_amdgcn_ds_bpermute(addr, pk[mi][2 * kc + 1][jj]);
            dw[av * 2 + jj] = hi ? t1 : t0;
          }
        }
        pa[mi][kc] = __builtin_bit_cast(bf16x8, dw);
      }

    // ---- PV: O += P @ V
    __builtin_amdgcn_s_setprio(1);
#pragma unroll
    for (int d = 0; d < 8; ++d)
#pragma unroll
      for (int kc = 0; kc < 2; ++kc){
        bf16x8 vf = *(const bf16x8*)&Vl[(d * 16 + lr) * 64 + ((kc * 32 + lg * 8) ^ swz)];
        acc[0][d] = MFMA16(pa[0][kc], vf, acc[0][d]);
        acc[1][d] = MFMA16(pa[1][kc], vf, acc[1][d]);
      }
    __builtin_amdgcn_s_setprio(0);

    __syncthreads();
    cur ^= 1;
  }

  // ---- epilogue: full row-sum for q=lr, redistribute to acc rows, store
  const int b = bh >> 3, h = bh & 7;
#pragma unroll
  for (int mi = 0; mi < 2; ++mi){
    float ls = lsum[mi];
    ls += __shfl_xor(ls, 16);
    ls += __shfl_xor(ls, 32);
    float inv = 1.0f / ls;
#pragma unroll
    for (int r = 0; r < 4; ++r){
      float invr = __shfl(inv, 20 * lg + r);
      int grow = qbase + mi * 16 + lg * 4 + r;
      size_t base = ((size_t)b * 1024 + (size_t)h * 128 + (grow >> 3)) * 1024
                  + (size_t)(grow & 7) * 128;
#pragma unroll
      for (int d = 0; d < 8; ++d)
        O[base + d * 16 + lr] = f2bf(acc[mi][d][r] * invr);
    }
  }
}

extern "C" void kernel_launch(void* const* d_in, const int* in_sizes, int n_in,
                              void* d_out, int out_size, void* d_ws, size_t ws_size,
                              hipStream_t stream){
  const float* motion = (const float*)d_in[0];
  const float* scene  = (const float*)d_in[1];
  const float* Wq     = (const float*)d_in[2];
  const float* bq     = (const float*)d_in[3];
  const float* Wkv    = (const float*)d_in[4];
  const float* bkv    = (const float*)d_in[5];
  const float* Wout   = (const float*)d_in[6];
  const float* bout   = (const float*)d_in[7];
  float* out = (float*)d_out;

  char* ws = (char*)d_ws;
  const size_t MB = 1024 * 1024;
  short* WqT   = (short*)(ws + 0);        // 2 MB
  short* WkvT  = (short*)(ws + 2  * MB);  // 4 MB
  short* WoutT = (short*)(ws + 6  * MB);  // 2 MB
  short* mA    = (short*)(ws + 8  * MB);  // 16 MB motion bf16 (reused as attnO)
  short* sA    = (short*)(ws + 24 * MB);  // 32 MB scene bf16
  short* Qb    = (short*)(ws + 56 * MB);  // 16 MB
  short* Kb    = (short*)(ws + 72 * MB);  // 32 MB
  short* Vtb   = (short*)(ws + 104* MB);  // 32 MB  V transposed [bh][dh][n]
  short* attnO = mA;

  const float qscale = 0.03125f * 1.44269504088896341f;  // D^-0.5 * log2(e)

  k_prep_all<<<dim3(2048), 256, 0, stream>>>(Wq, Wkv, Wout, WqT, WkvT, WoutT);
  k_f2bf_all<<<dim3(12288), 256, 0, stream>>>(motion, scene, mA, sA);

  k_gemm<0><<<dim3(8, 64), 256, 0, stream>>>(mA, WqT, bq, qscale, Qb, nullptr, 8192, 1024, 1024);
  k_gemmKV<<<dim3(8, 64), 512, 0, stream>>>(sA, WkvT, bkv, Kb, Vtb);
  k_attn<<<dim3(8, 64), 256, 0, stream>>>(Qb, Kb, Vtb, attnO);
  k_gemm<2><<<dim3(8, 64), 256, 0, stream>>>(attnO, WoutT, bout, 1.0f, out, nullptr, 8192, 1024, 1024);
}